// Round 7
// baseline (485.660 us; speedup 1.0000x reference)
//
#include <hip/hip_runtime.h>
#include <math.h>

#define HWSZ (512*512)
#define EPSV 1e-5f

typedef _Float16 h8 __attribute__((ext_vector_type(8)));
typedef _Float16 h4 __attribute__((ext_vector_type(4)));
typedef _Float16 h2 __attribute__((ext_vector_type(2)));
typedef float    f32x4 __attribute__((ext_vector_type(4)));

__device__ __forceinline__ h8 as_h8(uint4 u) { return __builtin_bit_cast(h8, u); }

// ---------------------------------------------------------------------------
// NCHW fp32 -> HWC fp16. 64 px x 64 ch tile via LDS; packed u32 stores.
// ---------------------------------------------------------------------------
__global__ __launch_bounds__(256) void to_hwc_f16(const float* __restrict__ in,
                                                  unsigned* __restrict__ out32) {
    __shared__ float T[64 * 65];
    int tid = threadIdx.x;
    int pbase = blockIdx.x * 64;
    int p = tid & 63, cg = tid >> 6;
#pragma unroll
    for (int j = 0; j < 16; ++j) {
        int c = cg * 16 + j;
        T[p * 65 + c] = in[c * HWSZ + pbase + p];
    }
    __syncthreads();
    int px = tid >> 2, cb = (tid & 3) * 16;
#pragma unroll
    for (int j = 0; j < 8; ++j) {
        int c = cb + 2 * j;
        h2 v = {(_Float16)T[px * 65 + c], (_Float16)T[px * 65 + c + 1]};
        out32[(pbase + px) * 32 + (c >> 1)] = __builtin_bit_cast(unsigned, v);
    }
}

// ---------------------------------------------------------------------------
// Weight prep. Fragment-major coalesced layouts:
//   dcn: w[(o*64+c)*9+k] -> wT[k*4096 + (c>>3)*512 + o*8 + (c&7)]
//   off: w[(o*64+c)*9+k] -> wTo[k*2048 + (c>>3)*256 + o*8 + (c&7)], o<18 pad 0
// ---------------------------------------------------------------------------
__global__ __launch_bounds__(256) void prep_all(
        const float* __restrict__ dw1, const float* __restrict__ dw2,
        const float* __restrict__ ow1, const float* __restrict__ ow2,
        _Float16* __restrict__ wT1, _Float16* __restrict__ wT2,
        _Float16* __restrict__ wTo1, _Float16* __restrict__ wTo2) {
    int i = blockIdx.x * 256 + threadIdx.x;
    if (i < 36864) {
        int k = i / 4096, r = i % 4096, o = r >> 6, c = r & 63;
        wT1[k * 4096 + (c >> 3) * 512 + o * 8 + (c & 7)] = (_Float16)dw1[(o * 64 + c) * 9 + k];
    } else if (i < 73728) {
        int j = i - 36864;
        int k = j / 4096, r = j % 4096, o = r >> 6, c = r & 63;
        wT2[k * 4096 + (c >> 3) * 512 + o * 8 + (c & 7)] = (_Float16)dw2[(o * 64 + c) * 9 + k];
    } else if (i < 92160) {
        int j = i - 73728;
        int k = j / 2048, r = j % 2048, o = r >> 6, c = r & 63;
        wTo1[k * 2048 + (c >> 3) * 256 + o * 8 + (c & 7)] =
            (_Float16)((o < 18) ? ow1[(o * 64 + c) * 9 + k] : 0.f);
    } else if (i < 110592) {
        int j = i - 92160;
        int k = j / 2048, r = j % 2048, o = r >> 6, c = r & 63;
        wTo2[k * 2048 + (c >> 3) * 256 + o * 8 + (c & 7)] =
            (_Float16)((o < 18) ? ow2[(o * 64 + c) * 9 + k] : 0.f);
    }
}

// ---------------------------------------------------------------------------
// 3x3 conv 64->18 (pad 32) via MFMA. Tile (3 rows x 66 cols x 64ch) staged in
// LDS; all 18 B-frags hoisted (now coalesced fragment-major loads).
// ---------------------------------------------------------------------------
__global__ __launch_bounds__(256, 3) void conv3x3_off_mfma(
        const _Float16* __restrict__ in, const _Float16* __restrict__ wTo,
        const float* __restrict__ bias, _Float16* __restrict__ off) {
    __shared__ uint4 TILE[3 * 66 * 8];   // 25.3 KB

    int tid = threadIdx.x;
    int pbase = blockIdx.x * 64;
    int y = pbase >> 9, xblk = pbase & 511;
    int l = tid & 63, wv = tid >> 6;
    int lq = l & 15, quad = l >> 4;
    int wn = wv & 1, wm = wv >> 1;     // wave tile: 32 px x 16 n

    // hoist all 18 B fragments (coalesced: 16B/lane, contiguous per 16 lanes)
    h8 breg[18];
#pragma unroll
    for (int k = 0; k < 9; ++k)
#pragma unroll
        for (int kc = 0; kc < 2; ++kc)
            breg[k * 2 + kc] = *(const h8*)(wTo + k * 2048 + (kc * 4 + quad) * 256 + (wn * 16 + lq) * 8);

    // stage: 1584 16B tasks, batched into 7 independent predicated loads
    uint4 v[7];
#pragma unroll
    for (int i = 0; i < 7; ++i) {
        int t = tid + 256 * i;
        int row = t / 528, r = t - row * 528;
        int col = r >> 3, cc = r & 7;
        int sy = y + row - 1, sx = xblk + col - 1;
        bool ok = (t < 1584) && ((unsigned)sy < 512u) && ((unsigned)sx < 512u);
        v[i] = ok ? *(const uint4*)(in + (sy * 512 + sx) * 64 + cc * 8)
                  : make_uint4(0u, 0u, 0u, 0u);
    }
#pragma unroll
    for (int i = 0; i < 7; ++i) {
        int t = tid + 256 * i;
        if (t < 1584) {
            int row = t / 528, r = t - row * 528;
            int col = r >> 3, cc = r & 7;
            TILE[(row * 66 + col) * 8 + (cc ^ (col & 7))] = v[i];
        }
    }
    __syncthreads();

    f32x4 zero = {0.f, 0.f, 0.f, 0.f};
    f32x4 acc[2]; acc[0] = zero; acc[1] = zero;

#pragma unroll
    for (int k = 0; k < 9; ++k) {
        int ky = k / 3, kx = k % 3;
#pragma unroll
        for (int kc = 0; kc < 2; ++kc) {
#pragma unroll
            for (int tm = 0; tm < 2; ++tm) {
                int col = kx + wm * 32 + tm * 16 + lq;
                int cc0 = kc * 4 + quad;
                h8 a = as_h8(TILE[(ky * 66 + col) * 8 + (cc0 ^ (col & 7))]);
                acc[tm] = __builtin_amdgcn_mfma_f32_16x16x32_f16(a, breg[k * 2 + kc], acc[tm], 0, 0, 0);
            }
        }
    }

    int n = wn * 16 + lq;
    if (n < 18) {
        float bb = bias[n];
#pragma unroll
        for (int tm = 0; tm < 2; ++tm)
#pragma unroll
            for (int reg = 0; reg < 4; ++reg) {
                int px = wm * 32 + tm * 16 + quad * 4 + reg;
                off[(pbase + px) * 18 + n] = (_Float16)(acc[tm][reg] + bb);
            }
    }
}

// ---------------------------------------------------------------------------
// Deformable conv 3x3 64->64 + bias + BN + ReLU, wave-autonomous:
// wave w owns 16 px x 64 oc. Each lane gathers + blends its OWN MFMA A
// fragment in registers (no LDS for S, ZERO barriers in the tap loop).
// Corner gathers double-buffered (1-iter shadow); B single-buffered,
// issued before the corner prefetch so fine-grained vmcnt never drains it.
// ---------------------------------------------------------------------------
__global__ __launch_bounds__(256, 3) void dcn_fused(
        const _Float16* __restrict__ in, const _Float16* __restrict__ off,
        const _Float16* __restrict__ wTb, const float* __restrict__ bias,
        const float* __restrict__ gamma, const float* __restrict__ beta,
        const float* __restrict__ mean, const float* __restrict__ var,
        _Float16* __restrict__ out) {
    __shared__ h4    SW9[9 * 64];
    __shared__ int4  SI9[9 * 64];
    __shared__ float scl_s[64], sh_s[64];

    int tid = threadIdx.x;
    int pbase = blockIdx.x * 64;

    // cooperative meta phase (one barrier total)
    for (int t = tid; t < 576; t += 256) {
        int p = t & 63, k = t >> 6;
        int gp = pbase + p;
        int y = gp >> 9, x = gp & 511;
        h2 dv = *(const h2*)(off + gp * 18 + 2 * k);
        float py = (float)(y + k / 3 - 1) + (float)dv[0];
        float px = (float)(x + k % 3 - 1) + (float)dv[1];
        float y0f = floorf(py), x0f = floorf(px);
        float wy = py - y0f, wx = px - x0f;
        int y0 = (int)y0f, x0 = (int)x0f;
        int y1 = y0 + 1, x1 = x0 + 1;
        float vy0 = ((unsigned)y0 < 512u) ? 1.f : 0.f;
        float vy1 = ((unsigned)y1 < 512u) ? 1.f : 0.f;
        float vx0 = ((unsigned)x0 < 512u) ? 1.f : 0.f;
        float vx1 = ((unsigned)x1 < 512u) ? 1.f : 0.f;
        SW9[t] = (h4){(_Float16)((1.f - wy) * (1.f - wx) * vy0 * vx0),
                      (_Float16)((1.f - wy) * wx * vy0 * vx1),
                      (_Float16)(wy * (1.f - wx) * vy1 * vx0),
                      (_Float16)(wy * wx * vy1 * vx1)};
        int y0c = min(max(y0, 0), 511), y1c = min(max(y1, 0), 511);
        int x0c = min(max(x0, 0), 511), x1c = min(max(x1, 0), 511);
        SI9[t] = make_int4((y0c * 512 + x0c) * 64, (y0c * 512 + x1c) * 64,
                           (y1c * 512 + x0c) * 64, (y1c * 512 + x1c) * 64);
    }
    if (tid < 64) {
        float s = gamma[tid] * rsqrtf(var[tid] + EPSV);
        scl_s[tid] = s;
        sh_s[tid] = beta[tid] - mean[tid] * s + bias[tid] * s;
    }
    __syncthreads();   // meta ready; LAST barrier in the kernel

    int l = tid & 63, wv = tid >> 6;
    int lq = l & 15, quad = l >> 4;
    int p_local = wv * 16 + lq;        // pixel this lane's A-row maps to
    int koff0 = quad * 8;              // kc=0 channel offset for this lane
    int koff1 = quad * 8 + 32;         // kc=1

    h8 cA[8], cB[8];   // corner sets (double-buffered across taps)
    h8 bfr[8];         // B fragments for current tap [kc*4 + n16]

#define ISSUEC(SET, KK) do {                                   \
        int4 id = SI9[(KK) * 64 + p_local];                    \
        SET[0] = *(const h8*)(in + id.x + koff0);              \
        SET[1] = *(const h8*)(in + id.y + koff0);              \
        SET[2] = *(const h8*)(in + id.z + koff0);              \
        SET[3] = *(const h8*)(in + id.w + koff0);              \
        SET[4] = *(const h8*)(in + id.x + koff1);              \
        SET[5] = *(const h8*)(in + id.y + koff1);              \
        SET[6] = *(const h8*)(in + id.z + koff1);              \
        SET[7] = *(const h8*)(in + id.w + koff1);              \
    } while (0)

#define LOADB(KK) do {                                                        \
        const _Float16* wk = wTb + (KK) * 4096 + quad * 512 + lq * 8;         \
        bfr[0] = *(const h8*)(wk);                                            \
        bfr[1] = *(const h8*)(wk + 128);                                      \
        bfr[2] = *(const h8*)(wk + 256);                                      \
        bfr[3] = *(const h8*)(wk + 384);                                      \
        bfr[4] = *(const h8*)(wk + 2048);                                     \
        bfr[5] = *(const h8*)(wk + 2048 + 128);                               \
        bfr[6] = *(const h8*)(wk + 2048 + 256);                               \
        bfr[7] = *(const h8*)(wk + 2048 + 384);                               \
    } while (0)

    f32x4 zero = {0.f, 0.f, 0.f, 0.f};
    f32x4 acc[4]; acc[0] = zero; acc[1] = zero; acc[2] = zero; acc[3] = zero;

    ISSUEC(cA, 0);
#pragma unroll
    for (int k = 0; k < 9; ++k) {
        LOADB(k);                      // B for tap k (issued BEFORE prefetch)
        if (k < 8) {                   // corner prefetch for tap k+1
            if ((k & 1) == 0) ISSUEC(cB, k + 1);
            else              ISSUEC(cA, k + 1);
        }
        // blend tap k (corners issued one iteration ago -> vmcnt(16))
        h4 wg = SW9[k * 64 + p_local];
        const h8* cs = ((k & 1) == 0) ? cA : cB;
        h8 a0 = cs[0] * wg[0] + cs[1] * wg[1] + cs[2] * wg[2] + cs[3] * wg[3];
        h8 a1 = cs[4] * wg[0] + cs[5] * wg[1] + cs[6] * wg[2] + cs[7] * wg[3];
        // MFMA tap k
        acc[0] = __builtin_amdgcn_mfma_f32_16x16x32_f16(a0, bfr[0], acc[0], 0, 0, 0);
        acc[1] = __builtin_amdgcn_mfma_f32_16x16x32_f16(a0, bfr[1], acc[1], 0, 0, 0);
        acc[2] = __builtin_amdgcn_mfma_f32_16x16x32_f16(a0, bfr[2], acc[2], 0, 0, 0);
        acc[3] = __builtin_amdgcn_mfma_f32_16x16x32_f16(a0, bfr[3], acc[3], 0, 0, 0);
        acc[0] = __builtin_amdgcn_mfma_f32_16x16x32_f16(a1, bfr[4], acc[0], 0, 0, 0);
        acc[1] = __builtin_amdgcn_mfma_f32_16x16x32_f16(a1, bfr[5], acc[1], 0, 0, 0);
        acc[2] = __builtin_amdgcn_mfma_f32_16x16x32_f16(a1, bfr[6], acc[2], 0, 0, 0);
        acc[3] = __builtin_amdgcn_mfma_f32_16x16x32_f16(a1, bfr[7], acc[3], 0, 0, 0);
    }
#undef ISSUEC
#undef LOADB

    // epilogue: C/D layout col=lane&15 (oc within n-tile), row=quad*4+reg (px)
#pragma unroll
    for (int n16 = 0; n16 < 4; ++n16) {
        int o = n16 * 16 + lq;
        float scl = scl_s[o], sh = sh_s[o];
#pragma unroll
        for (int reg = 0; reg < 4; ++reg) {
            int px = wv * 16 + quad * 4 + reg;
            out[(pbase + px) * 64 + o] =
                (_Float16)fmaxf(fmaf(acc[n16][reg], scl, sh), 0.f);
        }
    }
}

// ---------------------------------------------------------------------------
// 1x1 conv 64->1 + bias (fp16 HWC in, fp32 out)
// ---------------------------------------------------------------------------
__global__ __launch_bounds__(256) void conv1x1_out(const _Float16* __restrict__ in,
                                                   const float* __restrict__ w,
                                                   const float* __restrict__ b,
                                                   float* __restrict__ out) {
    int p = blockIdx.x * 256 + threadIdx.x;
    float acc = b[0];
    const h8* ip = (const h8*)(in + p * 64);
#pragma unroll
    for (int j = 0; j < 8; ++j) {
        h8 v = ip[j];
#pragma unroll
        for (int e = 0; e < 8; ++e)
            acc = fmaf((float)v[e], w[j * 8 + e], acc);
    }
    out[p] = acc;
}

// ---------------------------------------------------------------------------
extern "C" void kernel_launch(void* const* d_in, const int* in_sizes, int n_in,
                              void* d_out, int out_size, void* d_ws, size_t ws_size,
                              hipStream_t stream) {
    const float* x      = (const float*)d_in[0];
    const float* off1_w = (const float*)d_in[1];
    const float* off1_b = (const float*)d_in[2];
    const float* dcn1_w = (const float*)d_in[3];
    const float* dcn1_b = (const float*)d_in[4];
    const float* bn1_g  = (const float*)d_in[5];
    const float* bn1_be = (const float*)d_in[6];
    const float* bn1_m  = (const float*)d_in[7];
    const float* bn1_v  = (const float*)d_in[8];
    const float* off2_w = (const float*)d_in[9];
    const float* off2_b = (const float*)d_in[10];
    const float* dcn2_w = (const float*)d_in[11];
    const float* dcn2_b = (const float*)d_in[12];
    const float* bn2_g  = (const float*)d_in[13];
    const float* bn2_be = (const float*)d_in[14];
    const float* bn2_m  = (const float*)d_in[15];
    const float* bn2_v  = (const float*)d_in[16];
    const float* conv_w = (const float*)d_in[17];
    const float* conv_b = (const float*)d_in[18];
    float* out = (float*)d_out;

    char* ws = (char*)d_ws;
    _Float16* xh   = (_Float16*)ws;                       // 32 MiB (reused as h2)
    _Float16* h1   = (_Float16*)(ws + 33554432);          // 32 MiB
    _Float16* offb = (_Float16*)(ws + 2 * 33554432);      // 9 MiB
    _Float16* wT1  = (_Float16*)(ws + 2 * 33554432 + 9437184);
    _Float16* wT2  = wT1 + 36864;
    _Float16* wTo1 = wT2 + 36864;
    _Float16* wTo2 = wTo1 + 18432;
    _Float16* h2 = xh;

    prep_all<<<432, 256, 0, stream>>>(dcn1_w, dcn2_w, off1_w, off2_w,
                                      wT1, wT2, wTo1, wTo2);
    to_hwc_f16<<<4096, 256, 0, stream>>>(x, (unsigned*)xh);

    conv3x3_off_mfma<<<4096, 256, 0, stream>>>(xh, wTo1, off1_b, offb);
    dcn_fused<<<4096, 256, 0, stream>>>(xh, offb, wT1, dcn1_b,
                                        bn1_g, bn1_be, bn1_m, bn1_v, h1);
    conv3x3_off_mfma<<<4096, 256, 0, stream>>>(h1, wTo2, off2_b, offb);
    dcn_fused<<<4096, 256, 0, stream>>>(h1, offb, wT2, dcn2_b,
                                        bn2_g, bn2_be, bn2_m, bn2_v, h2);
    conv1x1_out<<<1024, 256, 0, stream>>>(h2, conv_w, conv_b, out);
}

// Round 8
// 480.946 us; speedup vs baseline: 1.0098x; 1.0098x over previous
//
#include <hip/hip_runtime.h>
#include <math.h>

#define HWSZ (512*512)
#define EPSV 1e-5f

typedef _Float16 h8 __attribute__((ext_vector_type(8)));
typedef _Float16 h4 __attribute__((ext_vector_type(4)));
typedef _Float16 h2 __attribute__((ext_vector_type(2)));
typedef float    f32x4 __attribute__((ext_vector_type(4)));

__device__ __forceinline__ h8 as_h8(uint4 u) { return __builtin_bit_cast(h8, u); }

// ---------------------------------------------------------------------------
// NCHW fp32 -> HWC fp16. 64 px x 64 ch tile via LDS; packed u32 stores.
// ---------------------------------------------------------------------------
__global__ __launch_bounds__(256) void to_hwc_f16(const float* __restrict__ in,
                                                  unsigned* __restrict__ out32) {
    __shared__ float T[64 * 65];
    int tid = threadIdx.x;
    int pbase = blockIdx.x * 64;
    int p = tid & 63, cg = tid >> 6;
#pragma unroll
    for (int j = 0; j < 16; ++j) {
        int c = cg * 16 + j;
        T[p * 65 + c] = in[c * HWSZ + pbase + p];
    }
    __syncthreads();
    int px = tid >> 2, cb = (tid & 3) * 16;
#pragma unroll
    for (int j = 0; j < 8; ++j) {
        int c = cb + 2 * j;
        h2 v = {(_Float16)T[px * 65 + c], (_Float16)T[px * 65 + c + 1]};
        out32[(pbase + px) * 32 + (c >> 1)] = __builtin_bit_cast(unsigned, v);
    }
}

// ---------------------------------------------------------------------------
// Weight prep. Fragment-major coalesced layouts:
//   dcn: w[(o*64+c)*9+k] -> wT[k*4096 + (c>>3)*512 + o*8 + (c&7)]
//   off: w[(o*64+c)*9+k] -> wTo[k*2048 + (c>>3)*256 + o*8 + (c&7)], o<18 pad 0
// ---------------------------------------------------------------------------
__global__ __launch_bounds__(256) void prep_all(
        const float* __restrict__ dw1, const float* __restrict__ dw2,
        const float* __restrict__ ow1, const float* __restrict__ ow2,
        _Float16* __restrict__ wT1, _Float16* __restrict__ wT2,
        _Float16* __restrict__ wTo1, _Float16* __restrict__ wTo2) {
    int i = blockIdx.x * 256 + threadIdx.x;
    if (i < 36864) {
        int k = i / 4096, r = i % 4096, o = r >> 6, c = r & 63;
        wT1[k * 4096 + (c >> 3) * 512 + o * 8 + (c & 7)] = (_Float16)dw1[(o * 64 + c) * 9 + k];
    } else if (i < 73728) {
        int j = i - 36864;
        int k = j / 4096, r = j % 4096, o = r >> 6, c = r & 63;
        wT2[k * 4096 + (c >> 3) * 512 + o * 8 + (c & 7)] = (_Float16)dw2[(o * 64 + c) * 9 + k];
    } else if (i < 92160) {
        int j = i - 73728;
        int k = j / 2048, r = j % 2048, o = r >> 6, c = r & 63;
        wTo1[k * 2048 + (c >> 3) * 256 + o * 8 + (c & 7)] =
            (_Float16)((o < 18) ? ow1[(o * 64 + c) * 9 + k] : 0.f);
    } else if (i < 110592) {
        int j = i - 92160;
        int k = j / 2048, r = j % 2048, o = r >> 6, c = r & 63;
        wTo2[k * 2048 + (c >> 3) * 256 + o * 8 + (c & 7)] =
            (_Float16)((o < 18) ? ow2[(o * 64 + c) * 9 + k] : 0.f);
    }
}

// ---------------------------------------------------------------------------
// 3x3 conv 64->18 (pad 32) via MFMA. Tile staged in LDS; 18 B-frags hoisted
// to registers, PINNED with sched_barrier so the scheduler can't sink them.
// ---------------------------------------------------------------------------
__global__ __launch_bounds__(256, 3) void conv3x3_off_mfma(
        const _Float16* __restrict__ in, const _Float16* __restrict__ wTo,
        const float* __restrict__ bias, _Float16* __restrict__ off) {
    __shared__ uint4 TILE[3 * 66 * 8];   // 25.3 KB

    int tid = threadIdx.x;
    int pbase = blockIdx.x * 64;
    int y = pbase >> 9, xblk = pbase & 511;
    int l = tid & 63, wv = tid >> 6;
    int lq = l & 15, quad = l >> 4;
    int wn = wv & 1, wm = wv >> 1;     // wave tile: 32 px x 16 n

    // hoist all 18 B fragments (coalesced fragment-major loads)
    h8 breg[18];
#pragma unroll
    for (int k = 0; k < 9; ++k)
#pragma unroll
        for (int kc = 0; kc < 2; ++kc)
            breg[k * 2 + kc] = *(const h8*)(wTo + k * 2048 + (kc * 4 + quad) * 256 + (wn * 16 + lq) * 8);

    // stage: 1584 16B tasks, batched into 7 independent predicated loads
    uint4 v[7];
#pragma unroll
    for (int i = 0; i < 7; ++i) {
        int t = tid + 256 * i;
        int row = t / 528, r = t - row * 528;
        int col = r >> 3, cc = r & 7;
        int sy = y + row - 1, sx = xblk + col - 1;
        bool ok = (t < 1584) && ((unsigned)sy < 512u) && ((unsigned)sx < 512u);
        v[i] = ok ? *(const uint4*)(in + (sy * 512 + sx) * 64 + cc * 8)
                  : make_uint4(0u, 0u, 0u, 0u);
    }
    __builtin_amdgcn_sched_barrier(0);   // pin: all loads issued above this line

#pragma unroll
    for (int i = 0; i < 7; ++i) {
        int t = tid + 256 * i;
        if (t < 1584) {
            int row = t / 528, r = t - row * 528;
            int col = r >> 3, cc = r & 7;
            TILE[(row * 66 + col) * 8 + (cc ^ (col & 7))] = v[i];
        }
    }
    __syncthreads();

    f32x4 zero = {0.f, 0.f, 0.f, 0.f};
    f32x4 acc[2]; acc[0] = zero; acc[1] = zero;

#pragma unroll
    for (int k = 0; k < 9; ++k) {
        int ky = k / 3, kx = k % 3;
#pragma unroll
        for (int kc = 0; kc < 2; ++kc) {
#pragma unroll
            for (int tm = 0; tm < 2; ++tm) {
                int col = kx + wm * 32 + tm * 16 + lq;
                int cc0 = kc * 4 + quad;
                h8 a = as_h8(TILE[(ky * 66 + col) * 8 + (cc0 ^ (col & 7))]);
                acc[tm] = __builtin_amdgcn_mfma_f32_16x16x32_f16(a, breg[k * 2 + kc], acc[tm], 0, 0, 0);
            }
        }
    }

    int n = wn * 16 + lq;
    if (n < 18) {
        float bb = bias[n];
#pragma unroll
        for (int tm = 0; tm < 2; ++tm)
#pragma unroll
            for (int reg = 0; reg < 4; ++reg) {
                int px = wm * 32 + tm * 16 + quad * 4 + reg;
                off[(pbase + px) * 18 + n] = (_Float16)(acc[tm][reg] + bb);
            }
    }
}

// ---------------------------------------------------------------------------
// Deformable conv 3x3 64->64 + bias + BN + ReLU, wave-autonomous, ZERO
// barriers in the tap loop. Corners AND B double-buffered in registers;
// each iteration's load-issue block pinned with sched_barrier(0) so the
// prefetch actually stays a full iteration ahead (r7's VGPR=36 sinking fix).
// ---------------------------------------------------------------------------
__global__ __launch_bounds__(256, 3) void dcn_fused(
        const _Float16* __restrict__ in, const _Float16* __restrict__ off,
        const _Float16* __restrict__ wTb, const float* __restrict__ bias,
        const float* __restrict__ gamma, const float* __restrict__ beta,
        const float* __restrict__ mean, const float* __restrict__ var,
        _Float16* __restrict__ out) {
    __shared__ h4    SW9[9 * 64];
    __shared__ int4  SI9[9 * 64];
    __shared__ float scl_s[64], sh_s[64];

    int tid = threadIdx.x;
    int pbase = blockIdx.x * 64;

    // cooperative meta phase (one barrier total)
    for (int t = tid; t < 576; t += 256) {
        int p = t & 63, k = t >> 6;
        int gp = pbase + p;
        int y = gp >> 9, x = gp & 511;
        h2 dv = *(const h2*)(off + gp * 18 + 2 * k);
        float py = (float)(y + k / 3 - 1) + (float)dv[0];
        float px = (float)(x + k % 3 - 1) + (float)dv[1];
        float y0f = floorf(py), x0f = floorf(px);
        float wy = py - y0f, wx = px - x0f;
        int y0 = (int)y0f, x0 = (int)x0f;
        int y1 = y0 + 1, x1 = x0 + 1;
        float vy0 = ((unsigned)y0 < 512u) ? 1.f : 0.f;
        float vy1 = ((unsigned)y1 < 512u) ? 1.f : 0.f;
        float vx0 = ((unsigned)x0 < 512u) ? 1.f : 0.f;
        float vx1 = ((unsigned)x1 < 512u) ? 1.f : 0.f;
        SW9[t] = (h4){(_Float16)((1.f - wy) * (1.f - wx) * vy0 * vx0),
                      (_Float16)((1.f - wy) * wx * vy0 * vx1),
                      (_Float16)(wy * (1.f - wx) * vy1 * vx0),
                      (_Float16)(wy * wx * vy1 * vx1)};
        int y0c = min(max(y0, 0), 511), y1c = min(max(y1, 0), 511);
        int x0c = min(max(x0, 0), 511), x1c = min(max(x1, 0), 511);
        SI9[t] = make_int4((y0c * 512 + x0c) * 64, (y0c * 512 + x1c) * 64,
                           (y1c * 512 + x0c) * 64, (y1c * 512 + x1c) * 64);
    }
    if (tid < 64) {
        float s = gamma[tid] * rsqrtf(var[tid] + EPSV);
        scl_s[tid] = s;
        sh_s[tid] = beta[tid] - mean[tid] * s + bias[tid] * s;
    }
    __syncthreads();   // meta ready; LAST barrier in the kernel

    int l = tid & 63, wv = tid >> 6;
    int lq = l & 15, quad = l >> 4;
    int p_local = wv * 16 + lq;        // pixel this lane's A-row maps to
    int koff0 = quad * 8;              // kc=0 channel offset for this lane
    int koff1 = quad * 8 + 32;         // kc=1

    h8 cA[8], cB[8];   // corner sets, double-buffered across taps
    h8 bA[8], bB[8];   // B fragments, double-buffered across taps

#define ISSUEC(SET, KK) do {                                   \
        int4 id = SI9[(KK) * 64 + p_local];                    \
        SET[0] = *(const h8*)(in + id.x + koff0);              \
        SET[1] = *(const h8*)(in + id.y + koff0);              \
        SET[2] = *(const h8*)(in + id.z + koff0);              \
        SET[3] = *(const h8*)(in + id.w + koff0);              \
        SET[4] = *(const h8*)(in + id.x + koff1);              \
        SET[5] = *(const h8*)(in + id.y + koff1);              \
        SET[6] = *(const h8*)(in + id.z + koff1);              \
        SET[7] = *(const h8*)(in + id.w + koff1);              \
    } while (0)

#define LOADB(BS, KK) do {                                                    \
        const _Float16* wk = wTb + (KK) * 4096 + quad * 512 + lq * 8;         \
        BS[0] = *(const h8*)(wk);                                             \
        BS[1] = *(const h8*)(wk + 128);                                       \
        BS[2] = *(const h8*)(wk + 256);                                       \
        BS[3] = *(const h8*)(wk + 384);                                       \
        BS[4] = *(const h8*)(wk + 2048);                                      \
        BS[5] = *(const h8*)(wk + 2048 + 128);                                \
        BS[6] = *(const h8*)(wk + 2048 + 256);                                \
        BS[7] = *(const h8*)(wk + 2048 + 384);                                \
    } while (0)

    f32x4 zero = {0.f, 0.f, 0.f, 0.f};
    f32x4 acc[4]; acc[0] = zero; acc[1] = zero; acc[2] = zero; acc[3] = zero;

    // prologue: tap 0 in flight
    ISSUEC(cA, 0);
    LOADB(bA, 0);
#pragma unroll
    for (int k = 0; k < 9; ++k) {
        // issue tap k+1 (corners + B) into the free buffer set
        if (k < 8) {
            if ((k & 1) == 0) { ISSUEC(cB, k + 1); LOADB(bB, k + 1); }
            else              { ISSUEC(cA, k + 1); LOADB(bA, k + 1); }
        }
        __builtin_amdgcn_sched_barrier(0);   // pin: prefetch issued above

        // blend + MFMA tap k (its loads were issued one full iteration ago)
        h4 wg = SW9[k * 64 + p_local];
        const h8* cs = ((k & 1) == 0) ? cA : cB;
        const h8* bf = ((k & 1) == 0) ? bA : bB;
        h8 a0 = cs[0] * wg[0] + cs[1] * wg[1] + cs[2] * wg[2] + cs[3] * wg[3];
        h8 a1 = cs[4] * wg[0] + cs[5] * wg[1] + cs[6] * wg[2] + cs[7] * wg[3];
        acc[0] = __builtin_amdgcn_mfma_f32_16x16x32_f16(a0, bf[0], acc[0], 0, 0, 0);
        acc[1] = __builtin_amdgcn_mfma_f32_16x16x32_f16(a0, bf[1], acc[1], 0, 0, 0);
        acc[2] = __builtin_amdgcn_mfma_f32_16x16x32_f16(a0, bf[2], acc[2], 0, 0, 0);
        acc[3] = __builtin_amdgcn_mfma_f32_16x16x32_f16(a0, bf[3], acc[3], 0, 0, 0);
        acc[0] = __builtin_amdgcn_mfma_f32_16x16x32_f16(a1, bf[4], acc[0], 0, 0, 0);
        acc[1] = __builtin_amdgcn_mfma_f32_16x16x32_f16(a1, bf[5], acc[1], 0, 0, 0);
        acc[2] = __builtin_amdgcn_mfma_f32_16x16x32_f16(a1, bf[6], acc[2], 0, 0, 0);
        acc[3] = __builtin_amdgcn_mfma_f32_16x16x32_f16(a1, bf[7], acc[3], 0, 0, 0);
    }
#undef ISSUEC
#undef LOADB

    // epilogue: C/D layout col=lane&15 (oc within n-tile), row=quad*4+reg (px)
#pragma unroll
    for (int n16 = 0; n16 < 4; ++n16) {
        int o = n16 * 16 + lq;
        float scl = scl_s[o], sh = sh_s[o];
#pragma unroll
        for (int reg = 0; reg < 4; ++reg) {
            int px = wv * 16 + quad * 4 + reg;
            out[(pbase + px) * 64 + o] =
                (_Float16)fmaxf(fmaf(acc[n16][reg], scl, sh), 0.f);
        }
    }
}

// ---------------------------------------------------------------------------
// 1x1 conv 64->1 + bias (fp16 HWC in, fp32 out)
// ---------------------------------------------------------------------------
__global__ __launch_bounds__(256) void conv1x1_out(const _Float16* __restrict__ in,
                                                   const float* __restrict__ w,
                                                   const float* __restrict__ b,
                                                   float* __restrict__ out) {
    int p = blockIdx.x * 256 + threadIdx.x;
    float acc = b[0];
    const h8* ip = (const h8*)(in + p * 64);
#pragma unroll
    for (int j = 0; j < 8; ++j) {
        h8 v = ip[j];
#pragma unroll
        for (int e = 0; e < 8; ++e)
            acc = fmaf((float)v[e], w[j * 8 + e], acc);
    }
    out[p] = acc;
}

// ---------------------------------------------------------------------------
extern "C" void kernel_launch(void* const* d_in, const int* in_sizes, int n_in,
                              void* d_out, int out_size, void* d_ws, size_t ws_size,
                              hipStream_t stream) {
    const float* x      = (const float*)d_in[0];
    const float* off1_w = (const float*)d_in[1];
    const float* off1_b = (const float*)d_in[2];
    const float* dcn1_w = (const float*)d_in[3];
    const float* dcn1_b = (const float*)d_in[4];
    const float* bn1_g  = (const float*)d_in[5];
    const float* bn1_be = (const float*)d_in[6];
    const float* bn1_m  = (const float*)d_in[7];
    const float* bn1_v  = (const float*)d_in[8];
    const float* off2_w = (const float*)d_in[9];
    const float* off2_b = (const float*)d_in[10];
    const float* dcn2_w = (const float*)d_in[11];
    const float* dcn2_b = (const float*)d_in[12];
    const float* bn2_g  = (const float*)d_in[13];
    const float* bn2_be = (const float*)d_in[14];
    const float* bn2_m  = (const float*)d_in[15];
    const float* bn2_v  = (const float*)d_in[16];
    const float* conv_w = (const float*)d_in[17];
    const float* conv_b = (const float*)d_in[18];
    float* out = (float*)d_out;

    char* ws = (char*)d_ws;
    _Float16* xh   = (_Float16*)ws;                       // 32 MiB (reused as h2)
    _Float16* h1   = (_Float16*)(ws + 33554432);          // 32 MiB
    _Float16* offb = (_Float16*)(ws + 2 * 33554432);      // 9 MiB
    _Float16* wT1  = (_Float16*)(ws + 2 * 33554432 + 9437184);
    _Float16* wT2  = wT1 + 36864;
    _Float16* wTo1 = wT2 + 36864;
    _Float16* wTo2 = wTo1 + 18432;
    _Float16* h2 = xh;

    prep_all<<<432, 256, 0, stream>>>(dcn1_w, dcn2_w, off1_w, off2_w,
                                      wT1, wT2, wTo1, wTo2);
    to_hwc_f16<<<4096, 256, 0, stream>>>(x, (unsigned*)xh);

    conv3x3_off_mfma<<<4096, 256, 0, stream>>>(xh, wTo1, off1_b, offb);
    dcn_fused<<<4096, 256, 0, stream>>>(xh, offb, wT1, dcn1_b,
                                        bn1_g, bn1_be, bn1_m, bn1_v, h1);
    conv3x3_off_mfma<<<4096, 256, 0, stream>>>(h1, wTo2, off2_b, offb);
    dcn_fused<<<4096, 256, 0, stream>>>(h1, offb, wT2, dcn2_b,
                                        bn2_g, bn2_be, bn2_m, bn2_v, h2);
    conv1x1_out<<<1024, 256, 0, stream>>>(h2, conv_w, conv_b, out);
}